// Round 3
// baseline (408.033 us; speedup 1.0000x reference)
//
#include <hip/hip_runtime.h>
#include <hip/hip_bf16.h>

#define B_TOT 16384
#define T_LEN 512
// H = 15. 16 lanes per sequence; lane owns hidden unit u = lane&15 (unit 15 is a zero pad).

typedef float f32x2 __attribute__((ext_vector_type(2)));

__device__ __forceinline__ float fast_rcp(float x) { return __builtin_amdgcn_rcpf(x); }
__device__ __forceinline__ float sigm(float x) { return fast_rcp(1.0f + __expf(-x)); }
// tanh(x) = 2*sigmoid(2x) - 1 ; saturates correctly for |x| large
__device__ __forceinline__ float tanh_f(float x) { return fmaf(2.0f, fast_rcp(1.0f + __expf(-2.0f * x)), -1.0f); }

// Broadcast from lane (group_base + SRC) within each aligned 16-lane group.
// ds_swizzle BitMode: src = ((lane31 & 0x10) | SRC)  -> imm = (SRC<<5) | 0x10
template <int SRC>
__device__ __forceinline__ float bcast16(float v) {
  return __int_as_float(__builtin_amdgcn_ds_swizzle(__float_as_int(v), (SRC << 5) | 0x10));
}

// Packed dual-fp32 ops on register pairs
#define PK_FMA_ACC(d, w, v) \
  asm("v_pk_fma_f32 %0, %1, %2, %0" : "+v"(d) : "v"(w), "v"(v))
#define PK_MUL(d, w, v) \
  asm("v_pk_mul_f32 %0, %1, %2" : "=v"(d) : "v"(w), "v"(v))

// One sequence per 16 lanes; 4 seqs per wave; 16 seqs per 256-thread block.
// Lane holds its unit's 4 gate rows (i,f,g,o) packed as 9 float2 pairs each:
//   vv[0]={x0,x1} vv[1]={x2,h0} vv[2]={h1,h2} ... vv[8]={h13,h14}
__global__ __launch_bounds__(256, 4) void lstm_scan_kernel(
    const float* __restrict__ x, const float* __restrict__ W_ih,
    const float* __restrict__ W_hh, const float* __restrict__ b_ih,
    const float* __restrict__ b_hh, float* __restrict__ h_out) {
  const int lane = threadIdx.x & 63;
  const int wave = threadIdx.x >> 6;
  const int u = lane & 15;  // owned hidden unit
  const int s = lane >> 4;  // sequence within the wave
  const int b = blockIdx.x * 16 + wave * 4 + s;
  const bool valid = (u < 15);

  f32x2 Wp[4][9];  // packed weights, 72 VGPRs
  float bb[4];     // scalar biases
#pragma unroll
  for (int g = 0; g < 4; ++g) {
    const int row = g * 15 + (valid ? u : 0);
    float wih[3];
#pragma unroll
    for (int k = 0; k < 3; ++k) wih[k] = valid ? W_ih[row * 3 + k] : 0.0f;
    float whh[15];
#pragma unroll
    for (int k = 0; k < 15; ++k) whh[k] = valid ? W_hh[row * 15 + k] : 0.0f;
    Wp[g][0].x = wih[0];
    Wp[g][0].y = wih[1];
    Wp[g][1].x = wih[2];
    Wp[g][1].y = whh[0];
#pragma unroll
    for (int jj = 2; jj < 9; ++jj) {
      Wp[g][jj].x = whh[2 * jj - 3];
      Wp[g][jj].y = whh[2 * jj - 2];
    }
    bb[g] = valid ? (b_ih[row] + b_hh[row]) : 0.0f;
  }
  // Opaque defs: pin packed weights into arch VGPRs, kill remat/AGPR shuffling
#pragma unroll
  for (int g = 0; g < 4; ++g) {
#pragma unroll
    for (int jj = 0; jj < 9; ++jj) asm volatile("" : "+v"(Wp[g][jj]));
    asm volatile("" : "+v"(bb[g]));
  }

  f32x2 vv[9];
#pragma unroll
  for (int jj = 0; jj < 9; ++jj) {
    vv[jj].x = 0.0f;
    vv[jj].y = 0.0f;
  }
  float c = 0.0f, h = 0.0f;

  const float* xp = x + (size_t)b * (T_LEN * 3);
  float nx0 = xp[0], nx1 = xp[1], nx2 = xp[2];

  for (int t = 0; t < T_LEN; ++t) {
    vv[0].x = nx0;
    vv[0].y = nx1;
    vv[1].x = nx2;
    const float* np_ = xp + ((t < T_LEN - 1) ? 3 : 0);
    nx0 = np_[0];
    nx1 = np_[1];
    nx2 = np_[2];
    xp = np_;

    f32x2 a2[4];
#pragma unroll
    for (int g = 0; g < 4; ++g) PK_MUL(a2[g], Wp[g][0], vv[0]);
#pragma unroll
    for (int jj = 1; jj < 9; ++jj) {
#pragma unroll
      for (int g = 0; g < 4; ++g) PK_FMA_ACC(a2[g], Wp[g][jj], vv[jj]);
    }

    const float ig = sigm((a2[0].x + bb[0]) + a2[0].y);
    const float fg = sigm((a2[1].x + bb[1]) + a2[1].y);
    const float gg = tanh_f((a2[2].x + bb[2]) + a2[2].y);
    const float og = sigm((a2[3].x + bb[3]) + a2[3].y);
    c = fmaf(fg, c, ig * gg);
    h = og * tanh_f(c);

    // allgather: every lane broadcasts its own h; lane k owns unit k
    vv[1].y = bcast16<0>(h);   // h0
    vv[2].x = bcast16<1>(h);   // h1
    vv[2].y = bcast16<2>(h);   // h2
    vv[3].x = bcast16<3>(h);   // h3
    vv[3].y = bcast16<4>(h);   // h4
    vv[4].x = bcast16<5>(h);   // h5
    vv[4].y = bcast16<6>(h);   // h6
    vv[5].x = bcast16<7>(h);   // h7
    vv[5].y = bcast16<8>(h);   // h8
    vv[6].x = bcast16<9>(h);   // h9
    vv[6].y = bcast16<10>(h);  // h10
    vv[7].x = bcast16<11>(h);  // h11
    vv[7].y = bcast16<12>(h);  // h12
    vv[8].x = bcast16<13>(h);  // h13
    vv[8].y = bcast16<14>(h);  // h14
  }

  // write last h: [B][16] layout; lane u=15 naturally has h==0 (all-zero row)
  h_out[(size_t)b * 16 + u] = h;
}

// Head: y = relu(h @ W1^T + b1) @ W2^T + b2. Block = 256 threads handles 64 batch rows;
// each row by 4 threads (16 output units each).
__global__ __launch_bounds__(256) void head_mlp_kernel(
    const float* __restrict__ h_ws, const float* __restrict__ W1,
    const float* __restrict__ b1, const float* __restrict__ W2,
    const float* __restrict__ b2, float* __restrict__ out) {
  __shared__ float sW1[64][17];
  __shared__ float sW2[64][65];
  __shared__ float sh[64][17];
  __shared__ float sy[64][65];
  __shared__ float sb1[64];
  __shared__ float sb2[64];

  const int tid = threadIdx.x;
  for (int i = tid; i < 64 * 16; i += 256) {
    const int u = i >> 4, k = i & 15;
    sW1[u][k] = (k < 15) ? W1[u * 15 + k] : 0.0f;
  }
  if (tid < 64) {
    sb1[tid] = b1[tid];
    sb2[tid] = b2[tid];
  }
  for (int i = tid; i < 64 * 64; i += 256) sW2[i >> 6][i & 63] = W2[i];
  for (int i = tid; i < 64 * 16; i += 256) sh[i >> 4][i & 15] = h_ws[(size_t)blockIdx.x * 1024 + i];
  __syncthreads();

  const int r = tid >> 2;  // local batch row
  const int q = tid & 3;   // quarter of the 64 outputs

  float y1v[16];
#pragma unroll
  for (int j = 0; j < 16; ++j) {
    const int u = q * 16 + j;
    float a = sb1[u];
#pragma unroll
    for (int k = 0; k < 15; ++k) a = fmaf(sW1[u][k], sh[r][k], a);
    y1v[j] = fmaxf(a, 0.0f);
  }
#pragma unroll
  for (int j = 0; j < 16; ++j) sy[r][q * 16 + j] = y1v[j];
  __syncthreads();

  float yv[64];
#pragma unroll
  for (int k = 0; k < 64; ++k) yv[k] = sy[r][k];
  float o[16];
#pragma unroll
  for (int j = 0; j < 16; ++j) {
    const int u = q * 16 + j;
    float a = sb2[u];
#pragma unroll
    for (int k = 0; k < 64; ++k) a = fmaf(sW2[u][k], yv[k], a);
    o[j] = a;
  }

  float* op = out + ((size_t)(blockIdx.x * 64 + r)) * 64 + q * 16;
#pragma unroll
  for (int j = 0; j < 16; ++j) op[j] = o[j];
}

extern "C" void kernel_launch(void* const* d_in, const int* in_sizes, int n_in,
                              void* d_out, int out_size, void* d_ws, size_t ws_size,
                              hipStream_t stream) {
  (void)in_sizes;
  (void)n_in;
  (void)out_size;
  (void)ws_size;
  const float* x = (const float*)d_in[0];
  const float* W_ih = (const float*)d_in[1];
  const float* W_hh = (const float*)d_in[2];
  const float* b_ih = (const float*)d_in[3];
  const float* b_hh = (const float*)d_in[4];
  const float* W1 = (const float*)d_in[5];
  const float* b1 = (const float*)d_in[6];
  const float* W2 = (const float*)d_in[7];
  const float* b2 = (const float*)d_in[8];
  float* out = (float*)d_out;
  float* h_ws = (float*)d_ws;  // [B][16] floats = 1 MB

  lstm_scan_kernel<<<B_TOT / 16, 256, 0, stream>>>(x, W_ih, W_hh, b_ih, b_hh, h_ws);
  head_mlp_kernel<<<B_TOT / 64, 256, 0, stream>>>(h_ws, W1, b1, W2, b2, out);
}

// Round 4
// 275.608 us; speedup vs baseline: 1.4805x; 1.4805x over previous
//
#include <hip/hip_runtime.h>
#include <hip/hip_bf16.h>

#define B_TOT 16384
#define T_LEN 512
// H = 15 padded to 16 units. Wave handles 16 sequences via MFMA:
// D[gate-row 16][seq 16] = A(weights bf16)[16,32] * B(state bf16)[32,16] + C(bias f32)
// 4 gate-blocks (i,f,g,o) x 2 K-halves = 8 MFMAs/step.
// Split precision: h = h_hi + h_lo (bf16 each), W = W_hi + W_lo (bf16 each).
// MFMA1 k-slots: [h_hi(16) x W_hi | h_lo(16) x W_hi]
// MFMA2 k-slots: [h_hi(16) x W_lo | x_hi(3) x Wih_hi | x_lo(3) x Wih_hi | x_hi(3) x Wih_lo | 0...]

typedef float f32x4 __attribute__((ext_vector_type(4)));
typedef short bf16x8 __attribute__((ext_vector_type(8)));
typedef unsigned int u32;
typedef u32 u32x4 __attribute__((ext_vector_type(4)));

__device__ __forceinline__ float fast_rcp(float x) { return __builtin_amdgcn_rcpf(x); }
__device__ __forceinline__ float sigm(float x) { return fast_rcp(1.0f + __expf(-x)); }
// tanh(x) = 2*sigmoid(2x) - 1 ; saturates correctly for |x| large
__device__ __forceinline__ float tanh_f(float x) { return fmaf(2.0f, fast_rcp(1.0f + __expf(-2.0f * x)), -1.0f); }

__device__ __forceinline__ unsigned short f32_to_bf16_rne(float f) {
  u32 u = __float_as_uint(f);
  u = u + 0x7fffu + ((u >> 16) & 1u);
  return (unsigned short)(u >> 16);
}
__device__ __forceinline__ float bf16u_to_f32(unsigned short s) {
  return __uint_as_float(((u32)s) << 16);
}
// packed f32->bf16x2: low16 = bf16(a), high16 = bf16(b)
__device__ __forceinline__ u32 cvt_pk_bf16(float a, float b) {
  u32 r;
  asm("v_cvt_pk_bf16_f32 %0, %1, %2" : "=v"(r) : "v"(a), "v"(b));
  return r;
}

__global__ __launch_bounds__(256) void lstm_scan_mfma(
    const float* __restrict__ x, const float* __restrict__ W_ih,
    const float* __restrict__ W_hh, const float* __restrict__ b_ih,
    const float* __restrict__ b_hh, float* __restrict__ h_out) {
  __shared__ uint4 sbuf[256];  // per-lane 16B: {ph0, ph1, pl0, pl1}
  const int tid = threadIdx.x;
  const int lane = tid & 63;
  const int wave = tid >> 6;
  const int hi = lane >> 4;   // k-slice selector for A/B fragments
  const int cs = lane & 15;   // A-row (unit) == B/C-col (seq slot)
  const int seq = blockIdx.x * 64 + wave * 16 + cs;
  const int u = cs;  // weight unit-row this lane supplies for A

  // ---- static A fragments (weights, hi/lo split) + bias accum-init ----
  bf16x8 A1[4], A2[4];
  f32x4 cbias[4];
#pragma unroll
  for (int g = 0; g < 4; ++g) {
#pragma unroll
    for (int e = 0; e < 8; ++e) {
      const int k = 8 * hi + e;
      // A1: W_hh hi-part at kk = k & 15 (same weights both K-halves)
      const int kk = k & 15;
      float w1 = (u < 15 && kk < 15) ? W_hh[(g * 15 + u) * 15 + kk] : 0.0f;
      A1[g][e] = (short)f32_to_bf16_rne(w1);
      // A2 per k-slot map
      float v = 0.0f;
      if (u < 15) {
        if (k < 15) {  // W_hh lo-part
          float w = W_hh[(g * 15 + u) * 15 + k];
          v = w - bf16u_to_f32(f32_to_bf16_rne(w));
        } else if (k >= 16 && k <= 18) {  // Wih_hi (x_hi slots)
          v = W_ih[(g * 15 + u) * 3 + (k - 16)];
        } else if (k >= 19 && k <= 21) {  // Wih_hi (x_lo slots)
          v = W_ih[(g * 15 + u) * 3 + (k - 19)];
        } else if (k >= 22 && k <= 24) {  // Wih_lo (x_hi slots)
          float w = W_ih[(g * 15 + u) * 3 + (k - 22)];
          v = w - bf16u_to_f32(f32_to_bf16_rne(w));
        }
      }
      A2[g][e] = (short)f32_to_bf16_rne(v);
    }
#pragma unroll
    for (int r = 0; r < 4; ++r) {
      const int uu = 4 * hi + r;  // C-row: unit index
      cbias[g][r] = (uu < 15) ? (b_ih[g * 15 + uu] + b_hh[g * 15 + uu]) : 0.0f;
    }
  }

  // ---- LDS addressing (uint2 granularity), precomputed ----
  uint2* p2 = reinterpret_cast<uint2*>(sbuf);
  const int wbase2 = wave * 128;  // 64 lanes * 16B / 8
  const int srcA = 2 * (hi & 1);  // source lane-group
  const int word2 = hi >> 1;      // 0: hi-packs, 1: lo-packs
  const int idxA = wbase2 + (srcA * 16 + cs) * 2 + word2;
  const int idxB = idxA + 32;  // +16 lanes

  sbuf[tid] = make_uint4(0u, 0u, 0u, 0u);  // h=0 initial state

  float carr[4] = {0.0f, 0.0f, 0.0f, 0.0f};
  float harr[4] = {0.0f, 0.0f, 0.0f, 0.0f};

  const float* xb = x + (size_t)seq * (T_LEN * 3);
  float nx0 = xb[0], nx1 = xb[1], nx2 = xb[2];

  const bool lo_half = (hi < 2);
  const bool is2 = (hi == 2);

  for (int t = 0; t < T_LEN; ++t) {
    // previous iteration's ds_write must complete before our reads (same wave)
    asm volatile("s_waitcnt lgkmcnt(0)" ::: "memory");
    __builtin_amdgcn_sched_barrier(0);
    const uint2 ra = p2[idxA];
    const uint2 rb = p2[idxB];

    // current x, prefetch next
    const float xc0 = nx0, xc1 = nx1, xc2 = nx2;
    {
      const int tn = (t + 1 < T_LEN) ? (t + 1) : t;
      nx0 = xb[tn * 3 + 0];
      nx1 = xb[tn * 3 + 1];
      nx2 = xb[tn * 3 + 2];
    }

    // x hi/lo packs for MFMA2 B-operand (lanes hi>=2)
    const u32 xr0 = cvt_pk_bf16(xc0, xc1);  // (xhi0, xhi1) -> k16,17 and k22,23
    const float xh0 = __uint_as_float(xr0 << 16);
    const float xh1 = __uint_as_float(xr0 & 0xffff0000u);
    const float xl0 = xc0 - xh0;
    const float xl1 = xc1 - xh1;
    const u32 xr1 = cvt_pk_bf16(xc2, xl0);  // (xhi2, xlo0) -> k18,19
    const float xh2 = __uint_as_float(xr1 << 16);
    const float xl2 = xc2 - xh2;
    const u32 xr2 = cvt_pk_bf16(xl1, xl2);  // (xlo1, xlo2) -> k20,21
    const u32 xt0 = xr1 & 0x0000ffffu;      // (xhi2, 0)    -> k24

    // B fragments
    u32 q0 = lo_half ? ra.x : (is2 ? xr0 : xt0);
    u32 q1 = lo_half ? ra.y : (is2 ? xr1 : 0u);
    u32 q2 = lo_half ? rb.x : (is2 ? xr2 : 0u);
    u32 q3 = lo_half ? rb.y : (is2 ? xr0 : 0u);
    const bf16x8 Bf1 = __builtin_bit_cast(bf16x8, (u32x4){ra.x, ra.y, rb.x, rb.y});
    const bf16x8 Bf2 = __builtin_bit_cast(bf16x8, (u32x4){q0, q1, q2, q3});

    // 8 MFMAs: gates i,f,g,o
    f32x4 acc0 = __builtin_amdgcn_mfma_f32_16x16x32_bf16(A1[0], Bf1, cbias[0], 0, 0, 0);
    f32x4 acc1 = __builtin_amdgcn_mfma_f32_16x16x32_bf16(A1[1], Bf1, cbias[1], 0, 0, 0);
    f32x4 acc2 = __builtin_amdgcn_mfma_f32_16x16x32_bf16(A1[2], Bf1, cbias[2], 0, 0, 0);
    f32x4 acc3 = __builtin_amdgcn_mfma_f32_16x16x32_bf16(A1[3], Bf1, cbias[3], 0, 0, 0);
    acc0 = __builtin_amdgcn_mfma_f32_16x16x32_bf16(A2[0], Bf2, acc0, 0, 0, 0);
    acc1 = __builtin_amdgcn_mfma_f32_16x16x32_bf16(A2[1], Bf2, acc1, 0, 0, 0);
    acc2 = __builtin_amdgcn_mfma_f32_16x16x32_bf16(A2[2], Bf2, acc2, 0, 0, 0);
    acc3 = __builtin_amdgcn_mfma_f32_16x16x32_bf16(A2[3], Bf2, acc3, 0, 0, 0);

    // activations: lane holds gates for units 4*hi+r of seq cs
#pragma unroll
    for (int r = 0; r < 4; ++r) {
      const float ig = sigm(acc0[r]);
      const float fg = sigm(acc1[r]);
      const float gg = tanh_f(acc2[r]);
      const float og = sigm(acc3[r]);
      carr[r] = fmaf(fg, carr[r], ig * gg);
      harr[r] = og * tanh_f(carr[r]);
    }

    // pack h hi/lo and publish for next step
    const u32 ph0 = cvt_pk_bf16(harr[0], harr[1]);
    const u32 ph1 = cvt_pk_bf16(harr[2], harr[3]);
    const float e0 = harr[0] - __uint_as_float(ph0 << 16);
    const float e1 = harr[1] - __uint_as_float(ph0 & 0xffff0000u);
    const float e2 = harr[2] - __uint_as_float(ph1 << 16);
    const float e3 = harr[3] - __uint_as_float(ph1 & 0xffff0000u);
    const u32 pl0 = cvt_pk_bf16(e0, e1);
    const u32 pl1 = cvt_pk_bf16(e2, e3);
    sbuf[tid] = make_uint4(ph0, ph1, pl0, pl1);
  }

  // write last h (f32): lane (hi, cs) holds units 4hi..4hi+3 of seq; unit 15 == 0
  float4 outv = make_float4(harr[0], harr[1], harr[2], harr[3]);
  *reinterpret_cast<float4*>(h_out + (size_t)seq * 16 + 4 * hi) = outv;
}

// Head: y = relu(h @ W1^T + b1) @ W2^T + b2. Block = 256 threads handles 64 batch rows;
// each row by 4 threads (16 output units each).
__global__ __launch_bounds__(256) void head_mlp_kernel(
    const float* __restrict__ h_ws, const float* __restrict__ W1,
    const float* __restrict__ b1, const float* __restrict__ W2,
    const float* __restrict__ b2, float* __restrict__ out) {
  __shared__ float sW1[64][17];
  __shared__ float sW2[64][65];
  __shared__ float sh[64][17];
  __shared__ float sy[64][65];
  __shared__ float sb1[64];
  __shared__ float sb2[64];

  const int tid = threadIdx.x;
  for (int i = tid; i < 64 * 16; i += 256) {
    const int u = i >> 4, k = i & 15;
    sW1[u][k] = (k < 15) ? W1[u * 15 + k] : 0.0f;
  }
  if (tid < 64) {
    sb1[tid] = b1[tid];
    sb2[tid] = b2[tid];
  }
  for (int i = tid; i < 64 * 64; i += 256) sW2[i >> 6][i & 63] = W2[i];
  for (int i = tid; i < 64 * 16; i += 256) sh[i >> 4][i & 15] = h_ws[(size_t)blockIdx.x * 1024 + i];
  __syncthreads();

  const int r = tid >> 2;  // local batch row
  const int q = tid & 3;   // quarter of the 64 outputs

  float y1v[16];
#pragma unroll
  for (int j = 0; j < 16; ++j) {
    const int u = q * 16 + j;
    float a = sb1[u];
#pragma unroll
    for (int k = 0; k < 15; ++k) a = fmaf(sW1[u][k], sh[r][k], a);
    y1v[j] = fmaxf(a, 0.0f);
  }
#pragma unroll
  for (int j = 0; j < 16; ++j) sy[r][q * 16 + j] = y1v[j];
  __syncthreads();

  float yv[64];
#pragma unroll
  for (int k = 0; k < 64; ++k) yv[k] = sy[r][k];
  float o[16];
#pragma unroll
  for (int j = 0; j < 16; ++j) {
    const int u = q * 16 + j;
    float a = sb2[u];
#pragma unroll
    for (int k = 0; k < 64; ++k) a = fmaf(sW2[u][k], yv[k], a);
    o[j] = a;
  }

  float* op = out + ((size_t)(blockIdx.x * 64 + r)) * 64 + q * 16;
#pragma unroll
  for (int j = 0; j < 16; ++j) op[j] = o[j];
}

extern "C" void kernel_launch(void* const* d_in, const int* in_sizes, int n_in,
                              void* d_out, int out_size, void* d_ws, size_t ws_size,
                              hipStream_t stream) {
  (void)in_sizes;
  (void)n_in;
  (void)out_size;
  (void)ws_size;
  const float* x = (const float*)d_in[0];
  const float* W_ih = (const float*)d_in[1];
  const float* W_hh = (const float*)d_in[2];
  const float* b_ih = (const float*)d_in[3];
  const float* b_hh = (const float*)d_in[4];
  const float* W1 = (const float*)d_in[5];
  const float* b1 = (const float*)d_in[6];
  const float* W2 = (const float*)d_in[7];
  const float* b2 = (const float*)d_in[8];
  float* out = (float*)d_out;
  float* h_ws = (float*)d_ws;  // [B][16] floats = 1 MB

  lstm_scan_mfma<<<B_TOT / 64, 256, 0, stream>>>(x, W_ih, W_hh, b_ih, b_hh, h_ws);
  head_mlp_kernel<<<B_TOT / 64, 256, 0, stream>>>(h_ws, W1, b1, W2, b2, out);
}

// Round 5
// 246.440 us; speedup vs baseline: 1.6557x; 1.1184x over previous
//
#include <hip/hip_runtime.h>
#include <hip/hip_bf16.h>

#define B_TOT 16384
#define T_LEN 512
// H = 15 padded to 16 units. Wave handles 16 sequences via MFMA:
// D[gate-row 16][seq 16] = A(weights bf16)[16,32] * B(state bf16)[32,16] + C(bias f32)
// 4 gate-blocks (i,f,g,o) x 2 K-halves = 8 MFMAs/step.
// Split precision: h = h_hi + h_lo (bf16 each), W = W_hi + W_lo (bf16 each).
// MFMA1 k-slots: [h_hi(16) x Whh_hi | h_lo(16) x Whh_hi]
// MFMA2 k-slots: [h_hi(16) x Whh_lo | x_hi(3)*Wih_hi | x_lo(3)*Wih_hi | x_hi(3)*Wih_lo | 0...]
// State redistribution between steps: pure in-register via
// v_permlane32_swap + v_permlane16_swap over lane quads {cs, cs+16, cs+32, cs+48}.

typedef float f32x4 __attribute__((ext_vector_type(4)));
typedef short bf16x8 __attribute__((ext_vector_type(8)));
typedef unsigned int u32;
typedef u32 u32x4 __attribute__((ext_vector_type(4)));

__device__ __forceinline__ float fast_rcp(float x) { return __builtin_amdgcn_rcpf(x); }
__device__ __forceinline__ float sigm(float x) { return fast_rcp(1.0f + __expf(-x)); }
// tanh(x) = 2*sigmoid(2x) - 1 ; saturates correctly for |x| large
__device__ __forceinline__ float tanh_f(float x) { return fmaf(2.0f, fast_rcp(1.0f + __expf(-2.0f * x)), -1.0f); }

__device__ __forceinline__ unsigned short f32_to_bf16_rne(float f) {
  u32 u = __float_as_uint(f);
  u = u + 0x7fffu + ((u >> 16) & 1u);
  return (unsigned short)(u >> 16);
}
__device__ __forceinline__ float bf16u_to_f32(unsigned short s) {
  return __uint_as_float(((u32)s) << 16);
}
// packed f32->bf16x2: low16 = bf16(a), high16 = bf16(b)
__device__ __forceinline__ u32 cvt_pk_bf16(float a, float b) {
  u32 r;
  asm("v_cvt_pk_bf16_f32 %0, %1, %2" : "=v"(r) : "v"(a), "v"(b));
  return r;
}

__global__ __launch_bounds__(256, 1) void lstm_scan_mfma(
    const float* __restrict__ x, const float* __restrict__ W_ih,
    const float* __restrict__ W_hh, const float* __restrict__ b_ih,
    const float* __restrict__ b_hh, float* __restrict__ h_out) {
  const int tid = threadIdx.x;
  const int lane = tid & 63;
  const int wave = tid >> 6;
  const int hi = lane >> 4;   // k-slice selector for A/B fragments
  const int cs = lane & 15;   // A-row (unit) == B/C-col (seq slot)
  const int seq = blockIdx.x * 64 + wave * 16 + cs;
  const int u = cs;  // weight unit-row this lane supplies for A

  // ---- static A fragments (weights, hi/lo split) + bias accum-init ----
  bf16x8 A1[4], A2[4];
  f32x4 cbias[4];
#pragma unroll
  for (int g = 0; g < 4; ++g) {
#pragma unroll
    for (int e = 0; e < 8; ++e) {
      const int k = 8 * hi + e;
      // A1: W_hh hi-part at kk = k & 15 (same weights both K-halves)
      const int kk = k & 15;
      float w1 = (u < 15 && kk < 15) ? W_hh[(g * 15 + u) * 15 + kk] : 0.0f;
      A1[g][e] = (short)f32_to_bf16_rne(w1);
      // A2 per k-slot map
      float v = 0.0f;
      if (u < 15) {
        if (k < 15) {  // W_hh lo-part
          float w = W_hh[(g * 15 + u) * 15 + k];
          v = w - bf16u_to_f32(f32_to_bf16_rne(w));
        } else if (k >= 16 && k <= 18) {  // Wih_hi (x_hi slots)
          v = W_ih[(g * 15 + u) * 3 + (k - 16)];
        } else if (k >= 19 && k <= 21) {  // Wih_hi (x_lo slots)
          v = W_ih[(g * 15 + u) * 3 + (k - 19)];
        } else if (k >= 22 && k <= 24) {  // Wih_lo (x_hi slots)
          float w = W_ih[(g * 15 + u) * 3 + (k - 22)];
          v = w - bf16u_to_f32(f32_to_bf16_rne(w));
        }
      }
      A2[g][e] = (short)f32_to_bf16_rne(v);
    }
#pragma unroll
    for (int r = 0; r < 4; ++r) {
      const int uu = 4 * hi + r;  // C-row: unit index
      cbias[g][r] = (uu < 15) ? (b_ih[g * 15 + uu] + b_hh[g * 15 + uu]) : 0.0f;
    }
  }

  float carr[4] = {0.0f, 0.0f, 0.0f, 0.0f};
  float harr[4] = {0.0f, 0.0f, 0.0f, 0.0f};
  // B-fragment words for the recurrent state (h == 0 initially)
  u32 w0 = 0u, w1 = 0u, w2 = 0u, w3 = 0u;

  const float* xb = x + (size_t)seq * (T_LEN * 3);
  float nx0 = xb[0], nx1 = xb[1], nx2 = xb[2];

  const bool lo_half = (hi < 2);
  const bool is2 = (hi == 2);

  for (int t = 0; t < T_LEN; ++t) {
    // current x, prefetch next
    const float xc0 = nx0, xc1 = nx1, xc2 = nx2;
    {
      const int tn = (t + 1 < T_LEN) ? (t + 1) : t;
      nx0 = xb[tn * 3 + 0];
      nx1 = xb[tn * 3 + 1];
      nx2 = xb[tn * 3 + 2];
    }

    // x hi/lo packs for MFMA2 B-operand (used by lanes hi>=2)
    const u32 xr0 = cvt_pk_bf16(xc0, xc1);  // (xhi0, xhi1) -> k16,17 and k22,23
    const float xh0 = __uint_as_float(xr0 << 16);
    const float xh1 = __uint_as_float(xr0 & 0xffff0000u);
    const float xl0 = xc0 - xh0;
    const float xl1 = xc1 - xh1;
    const u32 xr1 = cvt_pk_bf16(xc2, xl0);  // (xhi2, xlo0) -> k18,19
    const float xh2 = __uint_as_float(xr1 << 16);
    const float xl2 = xc2 - xh2;
    const u32 xr2 = cvt_pk_bf16(xl1, xl2);  // (xlo1, xlo2) -> k20,21
    const u32 xt0 = xr1 & 0x0000ffffu;      // (xhi2, 0)    -> k24

    // B fragments
    const u32 q0 = lo_half ? w0 : (is2 ? xr0 : xt0);
    const u32 q1 = lo_half ? w1 : (is2 ? xr1 : 0u);
    const u32 q2 = lo_half ? w2 : (is2 ? xr2 : 0u);
    const u32 q3 = lo_half ? w3 : (is2 ? xr0 : 0u);
    const bf16x8 Bf1 = __builtin_bit_cast(bf16x8, (u32x4){w0, w1, w2, w3});
    const bf16x8 Bf2 = __builtin_bit_cast(bf16x8, (u32x4){q0, q1, q2, q3});

    // 8 MFMAs: gates i,f,g,o
    f32x4 acc0 = __builtin_amdgcn_mfma_f32_16x16x32_bf16(A1[0], Bf1, cbias[0], 0, 0, 0);
    f32x4 acc1 = __builtin_amdgcn_mfma_f32_16x16x32_bf16(A1[1], Bf1, cbias[1], 0, 0, 0);
    f32x4 acc2 = __builtin_amdgcn_mfma_f32_16x16x32_bf16(A1[2], Bf1, cbias[2], 0, 0, 0);
    f32x4 acc3 = __builtin_amdgcn_mfma_f32_16x16x32_bf16(A1[3], Bf1, cbias[3], 0, 0, 0);
    acc0 = __builtin_amdgcn_mfma_f32_16x16x32_bf16(A2[0], Bf2, acc0, 0, 0, 0);
    acc1 = __builtin_amdgcn_mfma_f32_16x16x32_bf16(A2[1], Bf2, acc1, 0, 0, 0);
    acc2 = __builtin_amdgcn_mfma_f32_16x16x32_bf16(A2[2], Bf2, acc2, 0, 0, 0);
    acc3 = __builtin_amdgcn_mfma_f32_16x16x32_bf16(A2[3], Bf2, acc3, 0, 0, 0);

    // activations: lane holds gates for units 4*hi+r of seq cs
#pragma unroll
    for (int r = 0; r < 4; ++r) {
      const float ig = sigm(acc0[r]);
      const float fg = sigm(acc1[r]);
      const float gg = tanh_f(acc2[r]);
      const float og = sigm(acc3[r]);
      carr[r] = fmaf(fg, carr[r], ig * gg);
      harr[r] = og * tanh_f(carr[r]);
    }

    // pack h hi/lo
    u32 ph0 = cvt_pk_bf16(harr[0], harr[1]);
    u32 ph1 = cvt_pk_bf16(harr[2], harr[3]);
    const float e0 = harr[0] - __uint_as_float(ph0 << 16);
    const float e1 = harr[1] - __uint_as_float(ph0 & 0xffff0000u);
    const float e2 = harr[2] - __uint_as_float(ph1 << 16);
    const float e3 = harr[3] - __uint_as_float(ph1 & 0xffff0000u);
    u32 pl0 = cvt_pk_bf16(e0, e1);
    u32 pl1 = cvt_pk_bf16(e2, e3);

    // In-register redistribution across the lane quad {cs, cs+16, cs+32, cs+48}:
    //  after 2x permlane32_swap + 2x permlane16_swap:
    //   ph0 -> B-word0, ph1 -> B-word1, pl0 -> B-word2, pl1 -> B-word3
    asm volatile(
        "s_nop 1\n\t"
        "v_permlane32_swap_b32 %0, %2\n\t"
        "v_permlane32_swap_b32 %1, %3\n\t"
        "s_nop 0\n\t"
        "v_permlane16_swap_b32 %0, %2\n\t"
        "v_permlane16_swap_b32 %1, %3"
        : "+v"(ph0), "+v"(ph1), "+v"(pl0), "+v"(pl1));
    w0 = ph0;
    w1 = ph1;
    w2 = pl0;
    w3 = pl1;
  }

  // write last h (f32): lane (hi, cs) holds units 4hi..4hi+3 of seq; unit 15 == 0
  float4 outv = make_float4(harr[0], harr[1], harr[2], harr[3]);
  *reinterpret_cast<float4*>(h_out + (size_t)seq * 16 + 4 * hi) = outv;
}

// Head: y = relu(h @ W1^T + b1) @ W2^T + b2. Block = 256 threads handles 64 batch rows;
// each row by 4 threads (16 output units each).
__global__ __launch_bounds__(256) void head_mlp_kernel(
    const float* __restrict__ h_ws, const float* __restrict__ W1,
    const float* __restrict__ b1, const float* __restrict__ W2,
    const float* __restrict__ b2, float* __restrict__ out) {
  __shared__ float sW1[64][17];
  __shared__ float sW2[64][65];
  __shared__ float sh[64][17];
  __shared__ float sy[64][65];
  __shared__ float sb1[64];
  __shared__ float sb2[64];

  const int tid = threadIdx.x;
  for (int i = tid; i < 64 * 16; i += 256) {
    const int u = i >> 4, k = i & 15;
    sW1[u][k] = (k < 15) ? W1[u * 15 + k] : 0.0f;
  }
  if (tid < 64) {
    sb1[tid] = b1[tid];
    sb2[tid] = b2[tid];
  }
  for (int i = tid; i < 64 * 64; i += 256) sW2[i >> 6][i & 63] = W2[i];
  for (int i = tid; i < 64 * 16; i += 256) sh[i >> 4][i & 15] = h_ws[(size_t)blockIdx.x * 1024 + i];
  __syncthreads();

  const int r = tid >> 2;  // local batch row
  const int q = tid & 3;   // quarter of the 64 outputs

  float y1v[16];
#pragma unroll
  for (int j = 0; j < 16; ++j) {
    const int u = q * 16 + j;
    float a = sb1[u];
#pragma unroll
    for (int k = 0; k < 15; ++k) a = fmaf(sW1[u][k], sh[r][k], a);
    y1v[j] = fmaxf(a, 0.0f);
  }
#pragma unroll
  for (int j = 0; j < 16; ++j) sy[r][q * 16 + j] = y1v[j];
  __syncthreads();

  float yv[64];
#pragma unroll
  for (int k = 0; k < 64; ++k) yv[k] = sy[r][k];
  float o[16];
#pragma unroll
  for (int j = 0; j < 16; ++j) {
    const int u = q * 16 + j;
    float a = sb2[u];
#pragma unroll
    for (int k = 0; k < 64; ++k) a = fmaf(sW2[u][k], yv[k], a);
    o[j] = a;
  }

  float* op = out + ((size_t)(blockIdx.x * 64 + r)) * 64 + q * 16;
#pragma unroll
  for (int j = 0; j < 16; ++j) op[j] = o[j];
}

extern "C" void kernel_launch(void* const* d_in, const int* in_sizes, int n_in,
                              void* d_out, int out_size, void* d_ws, size_t ws_size,
                              hipStream_t stream) {
  (void)in_sizes;
  (void)n_in;
  (void)out_size;
  (void)ws_size;
  const float* x = (const float*)d_in[0];
  const float* W_ih = (const float*)d_in[1];
  const float* W_hh = (const float*)d_in[2];
  const float* b_ih = (const float*)d_in[3];
  const float* b_hh = (const float*)d_in[4];
  const float* W1 = (const float*)d_in[5];
  const float* b1 = (const float*)d_in[6];
  const float* W2 = (const float*)d_in[7];
  const float* b2 = (const float*)d_in[8];
  float* out = (float*)d_out;
  float* h_ws = (float*)d_ws;  // [B][16] floats = 1 MB

  lstm_scan_mfma<<<B_TOT / 64, 256, 0, stream>>>(x, W_ih, W_hh, b_ih, b_hh, h_ws);
  head_mlp_kernel<<<B_TOT / 64, 256, 0, stream>>>(h_ws, W1, b1, W2, b2, out);
}

// Round 6
// 237.241 us; speedup vs baseline: 1.7199x; 1.0388x over previous
//
#include <hip/hip_runtime.h>
#include <hip/hip_bf16.h>

#define B_TOT 16384
#define T_LEN 512
// H = 15 padded to 16 units. Wave handles 16 sequences via MFMA:
// D[gate-row 16][seq 16] = A(weights bf16)[16,32] * B(state bf16)[32,16] + C(bias f32)
// 4 gate-blocks (i,f,g,o) x 2 K-halves = 8 MFMAs/step.
// Split precision: h = h_hi + h_lo (bf16 each), W = W_hi + W_lo (bf16 each).
// MFMA1 k-slots: [h_hi(16) x Whh_hi | h_lo(16) x Whh_hi]
// MFMA2 k-slots: [h_hi(16) x Whh_lo | x_hi(3)*Wih_hi | x_lo(3)*Wih_hi | x_hi(3)*Wih_lo | 0...]
// Activation-scale folding: rows for gates i,f,o are pre-scaled by -log2e, gate g by
// +2*log2e, so sigma(a)=rcp(1+exp2(acc)) and tanh(a)=1-2*rcp(1+exp2(acc)) need no
// per-step argument multiply. Pairwise rcp trick: rcp(Di*Df) serves both sigmoids.
// State redistribution between steps: in-register v_permlane32/16_swap over lane quads.

typedef float f32x4 __attribute__((ext_vector_type(4)));
typedef short bf16x8 __attribute__((ext_vector_type(8)));
typedef unsigned int u32;
typedef u32 u32x4 __attribute__((ext_vector_type(4)));

#define LOG2E 1.4426950408889634f

__device__ __forceinline__ float fast_rcp(float x) { return __builtin_amdgcn_rcpf(x); }
__device__ __forceinline__ float exp2_hw(float x) {
  float r;
  asm("v_exp_f32 %0, %1" : "=v"(r) : "v"(x));
  return r;
}

__device__ __forceinline__ unsigned short f32_to_bf16_rne(float f) {
  u32 u = __float_as_uint(f);
  u = u + 0x7fffu + ((u >> 16) & 1u);
  return (unsigned short)(u >> 16);
}
__device__ __forceinline__ float bf16u_to_f32(unsigned short s) {
  return __uint_as_float(((u32)s) << 16);
}
// packed f32->bf16x2: low16 = bf16(a), high16 = bf16(b)
__device__ __forceinline__ u32 cvt_pk_bf16(float a, float b) {
  u32 r;
  asm("v_cvt_pk_bf16_f32 %0, %1, %2" : "=v"(r) : "v"(a), "v"(b));
  return r;
}

__global__ __launch_bounds__(256, 1) void lstm_scan_mfma(
    const float* __restrict__ x, const float* __restrict__ W_ih,
    const float* __restrict__ W_hh, const float* __restrict__ b_ih,
    const float* __restrict__ b_hh, float* __restrict__ h_out) {
  const int tid = threadIdx.x;
  const int lane = tid & 63;
  const int wave = tid >> 6;
  const int hi = lane >> 4;   // k-slice selector for A/B fragments
  const int cs = lane & 15;   // A-row (unit) == B/C-col (seq slot)
  const int seq = blockIdx.x * 64 + wave * 16 + cs;
  const int u = cs;  // weight unit-row this lane supplies for A

  // ---- static A fragments (scaled weights, hi/lo split) + bias accum-init ----
  bf16x8 A1[4], A2[4];
  f32x4 cbias[4];
#pragma unroll
  for (int g = 0; g < 4; ++g) {
    const float gs = (g == 2) ? (2.0f * LOG2E) : (-LOG2E);  // activation fold
#pragma unroll
    for (int e = 0; e < 8; ++e) {
      const int k = 8 * hi + e;
      // A1: scaled W_hh hi-part at kk = k & 15 (same weights both K-halves)
      const int kk = k & 15;
      float w1 = (u < 15 && kk < 15) ? gs * W_hh[(g * 15 + u) * 15 + kk] : 0.0f;
      A1[g][e] = (short)f32_to_bf16_rne(w1);
      // A2 per k-slot map
      float v = 0.0f;
      if (u < 15) {
        if (k < 15) {  // W_hh lo-part (of the SCALED weight)
          float w = gs * W_hh[(g * 15 + u) * 15 + k];
          v = w - bf16u_to_f32(f32_to_bf16_rne(w));
        } else if (k >= 16 && k <= 18) {  // Wih_hi (x_hi slots)
          v = gs * W_ih[(g * 15 + u) * 3 + (k - 16)];
        } else if (k >= 19 && k <= 21) {  // Wih_hi (x_lo slots)
          v = gs * W_ih[(g * 15 + u) * 3 + (k - 19)];
        } else if (k >= 22 && k <= 24) {  // Wih_lo (x_hi slots)
          float w = gs * W_ih[(g * 15 + u) * 3 + (k - 22)];
          v = w - bf16u_to_f32(f32_to_bf16_rne(w));
        }
      }
      A2[g][e] = (short)f32_to_bf16_rne(v);
    }
#pragma unroll
    for (int r = 0; r < 4; ++r) {
      const int uu = 4 * hi + r;  // C-row: unit index
      cbias[g][r] = (uu < 15) ? gs * (b_ih[g * 15 + uu] + b_hh[g * 15 + uu]) : 0.0f;
    }
  }

  float carr[4] = {0.0f, 0.0f, 0.0f, 0.0f};
  float harr[4] = {0.0f, 0.0f, 0.0f, 0.0f};
  // B-fragment words for the recurrent state (h == 0 initially)
  u32 w0 = 0u, w1 = 0u, w2 = 0u, w3 = 0u;

  const float* xb = x + (size_t)seq * (T_LEN * 3);
  float nx0 = xb[0], nx1 = xb[1], nx2 = xb[2];

  const bool lo_half = (hi < 2);
  const bool is2 = (hi == 2);

  for (int t = 0; t < T_LEN; ++t) {
    // current x, prefetch next
    const float xc0 = nx0, xc1 = nx1, xc2 = nx2;
    {
      const int tn = (t + 1 < T_LEN) ? (t + 1) : t;
      nx0 = xb[tn * 3 + 0];
      nx1 = xb[tn * 3 + 1];
      nx2 = xb[tn * 3 + 2];
    }

    // x hi/lo packs for MFMA2 B-operand (used by lanes hi>=2)
    const u32 xr0 = cvt_pk_bf16(xc0, xc1);  // (xhi0, xhi1) -> k16,17 and k22,23
    const float xh0 = __uint_as_float(xr0 << 16);
    const float xh1 = __uint_as_float(xr0 & 0xffff0000u);
    const float xl0 = xc0 - xh0;
    const float xl1 = xc1 - xh1;
    const u32 xr1 = cvt_pk_bf16(xc2, xl0);  // (xhi2, xlo0) -> k18,19
    const float xh2 = __uint_as_float(xr1 << 16);
    const float xl2 = xc2 - xh2;
    const u32 xr2 = cvt_pk_bf16(xl1, xl2);  // (xlo1, xlo2) -> k20,21
    const u32 xt0 = xr1 & 0x0000ffffu;      // (xhi2, 0)    -> k24

    // B fragments
    const u32 q0 = lo_half ? w0 : (is2 ? xr0 : xt0);
    const u32 q1 = lo_half ? w1 : (is2 ? xr1 : 0u);
    const u32 q2 = lo_half ? w2 : (is2 ? xr2 : 0u);
    const u32 q3 = lo_half ? w3 : (is2 ? xr0 : 0u);
    const bf16x8 Bf1 = __builtin_bit_cast(bf16x8, (u32x4){w0, w1, w2, w3});
    const bf16x8 Bf2 = __builtin_bit_cast(bf16x8, (u32x4){q0, q1, q2, q3});

    // 8 MFMAs: gates i,f,g,o (pre-activation already scale-folded)
    f32x4 acc0 = __builtin_amdgcn_mfma_f32_16x16x32_bf16(A1[0], Bf1, cbias[0], 0, 0, 0);
    f32x4 acc1 = __builtin_amdgcn_mfma_f32_16x16x32_bf16(A1[1], Bf1, cbias[1], 0, 0, 0);
    f32x4 acc2 = __builtin_amdgcn_mfma_f32_16x16x32_bf16(A1[2], Bf1, cbias[2], 0, 0, 0);
    f32x4 acc3 = __builtin_amdgcn_mfma_f32_16x16x32_bf16(A1[3], Bf1, cbias[3], 0, 0, 0);
    acc0 = __builtin_amdgcn_mfma_f32_16x16x32_bf16(A2[0], Bf2, acc0, 0, 0, 0);
    acc1 = __builtin_amdgcn_mfma_f32_16x16x32_bf16(A2[1], Bf2, acc1, 0, 0, 0);
    acc2 = __builtin_amdgcn_mfma_f32_16x16x32_bf16(A2[2], Bf2, acc2, 0, 0, 0);
    acc3 = __builtin_amdgcn_mfma_f32_16x16x32_bf16(A2[3], Bf2, acc3, 0, 0, 0);

    // activations: lane holds gates for units 4*hi+r of seq cs.
    // sigma(a) = rcp(1+exp2(acc_ifo)); tanh(a) = 1-2*rcp(1+exp2(acc_g)).
    // Pairwise rcp: one v_rcp serves two sigmoids.
#pragma unroll
    for (int r = 0; r < 4; ++r) {
      const float Di = 1.0f + exp2_hw(acc0[r]);
      const float Df = 1.0f + exp2_hw(acc1[r]);
      const float Dg = 1.0f + exp2_hw(acc2[r]);
      const float Do = 1.0f + exp2_hw(acc3[r]);
      const float r1 = fast_rcp(Di * Df);
      const float ig = r1 * Df;  // sigm(i)
      const float fg = r1 * Di;  // sigm(f)
      const float r2 = fast_rcp(Dg * Do);
      const float tg = fmaf(-2.0f, r2 * Do, 1.0f);  // tanh(g)
      const float og = r2 * Dg;                     // sigm(o)
      carr[r] = fmaf(fg, carr[r], ig * tg);
      const float cs2 = carr[r] * (2.0f * LOG2E);
      const float tc = fmaf(-2.0f, fast_rcp(1.0f + exp2_hw(cs2)), 1.0f);  // tanh(c), inf-safe
      harr[r] = og * tc;
    }

    // pack h hi/lo
    u32 ph0 = cvt_pk_bf16(harr[0], harr[1]);
    u32 ph1 = cvt_pk_bf16(harr[2], harr[3]);
    const float e0 = harr[0] - __uint_as_float(ph0 << 16);
    const float e1 = harr[1] - __uint_as_float(ph0 & 0xffff0000u);
    const float e2 = harr[2] - __uint_as_float(ph1 << 16);
    const float e3 = harr[3] - __uint_as_float(ph1 & 0xffff0000u);
    u32 pl0 = cvt_pk_bf16(e0, e1);
    u32 pl1 = cvt_pk_bf16(e2, e3);

    // In-register redistribution across the lane quad {cs, cs+16, cs+32, cs+48}:
    //  after 2x permlane32_swap + 2x permlane16_swap:
    //   ph0 -> B-word0, ph1 -> B-word1, pl0 -> B-word2, pl1 -> B-word3
    asm volatile(
        "s_nop 1\n\t"
        "v_permlane32_swap_b32 %0, %2\n\t"
        "v_permlane32_swap_b32 %1, %3\n\t"
        "s_nop 0\n\t"
        "v_permlane16_swap_b32 %0, %2\n\t"
        "v_permlane16_swap_b32 %1, %3"
        : "+v"(ph0), "+v"(ph1), "+v"(pl0), "+v"(pl1));
    w0 = ph0;
    w1 = ph1;
    w2 = pl0;
    w3 = pl1;
  }

  // write last h (f32): lane (hi, cs) holds units 4hi..4hi+3 of seq; unit 15 == 0
  float4 outv = make_float4(harr[0], harr[1], harr[2], harr[3]);
  *reinterpret_cast<float4*>(h_out + (size_t)seq * 16 + 4 * hi) = outv;
}

// Head: y = relu(h @ W1^T + b1) @ W2^T + b2. Block = 256 threads handles 64 batch rows;
// each row by 4 threads (16 output units each).
__global__ __launch_bounds__(256) void head_mlp_kernel(
    const float* __restrict__ h_ws, const float* __restrict__ W1,
    const float* __restrict__ b1, const float* __restrict__ W2,
    const float* __restrict__ b2, float* __restrict__ out) {
  __shared__ float sW1[64][17];
  __shared__ float sW2[64][65];
  __shared__ float sh[64][17];
  __shared__ float sy[64][65];
  __shared__ float sb1[64];
  __shared__ float sb2[64];

  const int tid = threadIdx.x;
  for (int i = tid; i < 64 * 16; i += 256) {
    const int u = i >> 4, k = i & 15;
    sW1[u][k] = (k < 15) ? W1[u * 15 + k] : 0.0f;
  }
  if (tid < 64) {
    sb1[tid] = b1[tid];
    sb2[tid] = b2[tid];
  }
  for (int i = tid; i < 64 * 64; i += 256) sW2[i >> 6][i & 63] = W2[i];
  for (int i = tid; i < 64 * 16; i += 256) sh[i >> 4][i & 15] = h_ws[(size_t)blockIdx.x * 1024 + i];
  __syncthreads();

  const int r = tid >> 2;  // local batch row
  const int q = tid & 3;   // quarter of the 64 outputs

  float y1v[16];
#pragma unroll
  for (int j = 0; j < 16; ++j) {
    const int u = q * 16 + j;
    float a = sb1[u];
#pragma unroll
    for (int k = 0; k < 15; ++k) a = fmaf(sW1[u][k], sh[r][k], a);
    y1v[j] = fmaxf(a, 0.0f);
  }
#pragma unroll
  for (int j = 0; j < 16; ++j) sy[r][q * 16 + j] = y1v[j];
  __syncthreads();

  float yv[64];
#pragma unroll
  for (int k = 0; k < 64; ++k) yv[k] = sy[r][k];
  float o[16];
#pragma unroll
  for (int j = 0; j < 16; ++j) {
    const int u = q * 16 + j;
    float a = sb2[u];
#pragma unroll
    for (int k = 0; k < 64; ++k) a = fmaf(sW2[u][k], yv[k], a);
    o[j] = a;
  }

  float* op = out + ((size_t)(blockIdx.x * 64 + r)) * 64 + q * 16;
#pragma unroll
  for (int j = 0; j < 16; ++j) op[j] = o[j];
}

extern "C" void kernel_launch(void* const* d_in, const int* in_sizes, int n_in,
                              void* d_out, int out_size, void* d_ws, size_t ws_size,
                              hipStream_t stream) {
  (void)in_sizes;
  (void)n_in;
  (void)out_size;
  (void)ws_size;
  const float* x = (const float*)d_in[0];
  const float* W_ih = (const float*)d_in[1];
  const float* W_hh = (const float*)d_in[2];
  const float* b_ih = (const float*)d_in[3];
  const float* b_hh = (const float*)d_in[4];
  const float* W1 = (const float*)d_in[5];
  const float* b1 = (const float*)d_in[6];
  const float* W2 = (const float*)d_in[7];
  const float* b2 = (const float*)d_in[8];
  float* out = (float*)d_out;
  float* h_ws = (float*)d_ws;  // [B][16] floats = 1 MB

  lstm_scan_mfma<<<B_TOT / 64, 256, 0, stream>>>(x, W_ih, W_hh, b_ih, b_hh, h_ws);
  head_mlp_kernel<<<B_TOT / 64, 256, 0, stream>>>(h_ws, W1, b1, W2, b2, out);
}

// Round 7
// 226.091 us; speedup vs baseline: 1.8047x; 1.0493x over previous
//
#include <hip/hip_runtime.h>
#include <hip/hip_bf16.h>

#define B_TOT 16384
#define T_LEN 512
// H = 15 padded to 16. Wave = 16 seqs. Per step:
//   gates[16 rows][16 seqs] = MFMA_h( A=[Whh_hi | Whh_lo], B=[h | h] ) + px
//   px = MFMA_x( A=Wih k-map, B=x packs ) + bias   <- state-independent, computed
//        one step AHEAD (double-buffered), so it overlaps the serial chain.
// Weight-split keeps full weight precision: (Whh_hi+Whh_lo)*bf16(h).
// Activation fold: i,f,o rows scaled by -log2e, g by +2log2e ->
//   sigma(a)=rcp(1+exp2(acc)), tanh(a)=1-2*rcp(1+exp2(acc)).
// State exchange: 2 movs + 2x permlane32_swap + 2x permlane16_swap produce the
// [h|h]-duplicated B fragment in-register (no LDS).

typedef float f32x4 __attribute__((ext_vector_type(4)));
typedef short bf16x8 __attribute__((ext_vector_type(8)));
typedef unsigned int u32;
typedef u32 u32x4 __attribute__((ext_vector_type(4)));

#define LOG2E 1.4426950408889634f

__device__ __forceinline__ float fast_rcp(float x) { return __builtin_amdgcn_rcpf(x); }
__device__ __forceinline__ float exp2_hw(float x) {
  float r;
  asm("v_exp_f32 %0, %1" : "=v"(r) : "v"(x));
  return r;
}
__device__ __forceinline__ unsigned short f32_to_bf16_rne(float f) {
  u32 u = __float_as_uint(f);
  u = u + 0x7fffu + ((u >> 16) & 1u);
  return (unsigned short)(u >> 16);
}
__device__ __forceinline__ float bf16u_to_f32(unsigned short s) {
  return __uint_as_float(((u32)s) << 16);
}
__device__ __forceinline__ u32 cvt_pk_bf16(float a, float b) {
  u32 r;
  asm("v_cvt_pk_bf16_f32 %0, %1, %2" : "=v"(r) : "v"(a), "v"(b));
  return r;
}

__global__ __launch_bounds__(256, 1) void lstm_scan_mfma(
    const float* __restrict__ x, const float* __restrict__ W_ih,
    const float* __restrict__ W_hh, const float* __restrict__ b_ih,
    const float* __restrict__ b_hh, float* __restrict__ h_out) {
  const int tid = threadIdx.x;
  const int lane = tid & 63;
  const int wave = tid >> 6;
  const int hi = lane >> 4;   // k-slice / C-row-block selector
  const int cs = lane & 15;   // A-row (unit) == B/C-col (seq slot)
  const int seq = blockIdx.x * 64 + wave * 16 + cs;
  const int u = cs;           // weight unit-row this lane supplies for A

  // ---- static A fragments + bias ----
  // Ah: k0-15 = bf16_hi(gs*Whh[u][k]); k16-31 = bf16_lo(gs*Whh[u][k-16])
  // Ax: k0-2 = Wih_hi, k3-5 = Wih_hi (x_lo slots), k6-8 = Wih_lo, else 0
  bf16x8 Ah[4], Ax[4];
  f32x4 cbias[4];
#pragma unroll
  for (int g = 0; g < 4; ++g) {
    const float gs = (g == 2) ? (2.0f * LOG2E) : (-LOG2E);
#pragma unroll
    for (int e = 0; e < 8; ++e) {
      const int k = 8 * hi + e;
      float vh = 0.0f, vx = 0.0f;
      if (u < 15) {
        if (k < 16) {
          if (k < 15) vh = bf16u_to_f32(f32_to_bf16_rne(gs * W_hh[(g * 15 + u) * 15 + k]));
        } else {
          const int kk = k - 16;
          if (kk < 15) {
            const float w = gs * W_hh[(g * 15 + u) * 15 + kk];
            vh = w - bf16u_to_f32(f32_to_bf16_rne(w));
          }
        }
        if (k < 3) {
          vx = gs * W_ih[(g * 15 + u) * 3 + k];
        } else if (k < 6) {
          vx = gs * W_ih[(g * 15 + u) * 3 + (k - 3)];
        } else if (k < 9) {
          const float w = gs * W_ih[(g * 15 + u) * 3 + (k - 6)];
          vx = w - bf16u_to_f32(f32_to_bf16_rne(w));
        }
      }
      Ah[g][e] = (short)f32_to_bf16_rne(vh);
      Ax[g][e] = (short)f32_to_bf16_rne(vx);
    }
#pragma unroll
    for (int r = 0; r < 4; ++r) {
      const int uu = 4 * hi + r;
      cbias[g][r] = (uu < 15) ? gs * (b_ih[g * 15 + uu] + b_hh[g * 15 + uu]) : 0.0f;
    }
  }

  float carr[4] = {0.0f, 0.0f, 0.0f, 0.0f};
  float harr[4] = {0.0f, 0.0f, 0.0f, 0.0f};
  u32 w0 = 0u, w1 = 0u, w2 = 0u, w3 = 0u;  // B state fragment (h==0)

  const float* xb = x + (size_t)seq * (T_LEN * 3);

  // helper: build Bx fragment words from an x triple (for gate px of that step)
  auto make_bx = [&](float xc0, float xc1, float xc2, u32& b0, u32& b1, u32& b2,
                     u32& b3) __attribute__((always_inline)) {
    const u32 xr0 = cvt_pk_bf16(xc0, xc1);  // (xh0, xh1): k0,1 and k6,7
    const float xh0 = __uint_as_float(xr0 << 16);
    const float xh1 = __uint_as_float(xr0 & 0xffff0000u);
    const float xl0 = xc0 - xh0;
    const float xl1 = xc1 - xh1;
    const u32 xr1 = cvt_pk_bf16(xc2, xl0);  // (xh2, xl0): k2,3
    const float xh2 = __uint_as_float(xr1 << 16);
    const float xl2 = xc2 - xh2;
    const u32 xr2 = cvt_pk_bf16(xl1, xl2);  // (xl1, xl2): k4,5
    const u32 xt0 = xr1 & 0x0000ffffu;      // (xh2, 0):   k8
    b0 = (hi == 0) ? xr0 : ((hi == 1) ? xt0 : 0u);
    b1 = (hi == 0) ? xr1 : 0u;
    b2 = (hi == 0) ? xr2 : 0u;
    b3 = (hi == 0) ? xr0 : 0u;
  };

  // ---- prologue: px(0) from x(0); prefetch x(1) ----
  f32x4 pxA[4], pxB[4];
  {
    const float x00 = xb[0], x01 = xb[1], x02 = xb[2];
    u32 b0, b1, b2, b3;
    make_bx(x00, x01, x02, b0, b1, b2, b3);
    const bf16x8 Bx = __builtin_bit_cast(bf16x8, (u32x4){b0, b1, b2, b3});
    pxA[0] = __builtin_amdgcn_mfma_f32_16x16x32_bf16(Ax[0], Bx, cbias[0], 0, 0, 0);
    pxA[1] = __builtin_amdgcn_mfma_f32_16x16x32_bf16(Ax[1], Bx, cbias[1], 0, 0, 0);
    pxA[2] = __builtin_amdgcn_mfma_f32_16x16x32_bf16(Ax[2], Bx, cbias[2], 0, 0, 0);
    pxA[3] = __builtin_amdgcn_mfma_f32_16x16x32_bf16(Ax[3], Bx, cbias[3], 0, 0, 0);
  }
  float nx0 = xb[3], nx1 = xb[4], nx2 = xb[5];  // x(1)

  // one time-step: consume PX (this step's x-proj), produce PXN (next step's)
  auto step = [&](f32x4(&PX)[4], f32x4(&PXN)[4],
                  int tcur) __attribute__((always_inline)) {
    // recurrent MFMA: gates = [Whh_hi|Whh_lo] * [h|h] + px
    const bf16x8 Bh = __builtin_bit_cast(bf16x8, (u32x4){w0, w1, w2, w3});
    f32x4 acc0 = __builtin_amdgcn_mfma_f32_16x16x32_bf16(Ah[0], Bh, PX[0], 0, 0, 0);
    f32x4 acc1 = __builtin_amdgcn_mfma_f32_16x16x32_bf16(Ah[1], Bh, PX[1], 0, 0, 0);
    f32x4 acc2 = __builtin_amdgcn_mfma_f32_16x16x32_bf16(Ah[2], Bh, PX[2], 0, 0, 0);
    f32x4 acc3 = __builtin_amdgcn_mfma_f32_16x16x32_bf16(Ah[3], Bh, PX[3], 0, 0, 0);

    // state-independent: px for step tcur+1 from x(tcur+1) (in nx*), overlaps chain
    {
      u32 b0, b1, b2, b3;
      make_bx(nx0, nx1, nx2, b0, b1, b2, b3);
      const bf16x8 Bx = __builtin_bit_cast(bf16x8, (u32x4){b0, b1, b2, b3});
      PXN[0] = __builtin_amdgcn_mfma_f32_16x16x32_bf16(Ax[0], Bx, cbias[0], 0, 0, 0);
      PXN[1] = __builtin_amdgcn_mfma_f32_16x16x32_bf16(Ax[1], Bx, cbias[1], 0, 0, 0);
      PXN[2] = __builtin_amdgcn_mfma_f32_16x16x32_bf16(Ax[2], Bx, cbias[2], 0, 0, 0);
      PXN[3] = __builtin_amdgcn_mfma_f32_16x16x32_bf16(Ax[3], Bx, cbias[3], 0, 0, 0);
    }
    // prefetch x(tcur+2)
    {
      const int tn = (tcur + 2 < T_LEN) ? (tcur + 2) : (T_LEN - 1);
      nx0 = xb[tn * 3 + 0];
      nx1 = xb[tn * 3 + 1];
      nx2 = xb[tn * 3 + 2];
    }

    // activations: sigma = rcp(1+exp2(.)), tanh = 1-2*rcp(1+exp2(.)); paired rcp
#pragma unroll
    for (int r = 0; r < 4; ++r) {
      const float Di = 1.0f + exp2_hw(acc0[r]);
      const float Df = 1.0f + exp2_hw(acc1[r]);
      const float Dg = 1.0f + exp2_hw(acc2[r]);
      const float Do = 1.0f + exp2_hw(acc3[r]);
      const float r1 = fast_rcp(Di * Df);
      const float ig = r1 * Df;
      const float fg = r1 * Di;
      const float r2 = fast_rcp(Dg * Do);
      const float tg = fmaf(-2.0f, r2 * Do, 1.0f);
      const float og = r2 * Dg;
      carr[r] = fmaf(fg, carr[r], ig * tg);
      const float cs2 = carr[r] * (2.0f * LOG2E);
      const float tc = fmaf(-2.0f, fast_rcp(1.0f + exp2_hw(cs2)), 1.0f);
      harr[r] = og * tc;
    }

    // pack h (single bf16) and exchange into the [h|h]-duplicated B fragment:
    // quad lane q holds ph0=(h4q,h4q+1), ph1=(h4q+2,h4q+3); after
    // {copy; P32; P16} each lane gets w0=ph0(q=2*b4), w1=ph1(q=2*b4),
    // w2=ph0(q=2*b4+1), w3=ph1(q=2*b4+1) -> exactly B k-slots [h|h].
    u32 ph0 = cvt_pk_bf16(harr[0], harr[1]);
    u32 ph1 = cvt_pk_bf16(harr[2], harr[3]);
    u32 c0, c1;
    asm volatile(
        "v_mov_b32 %2, %0\n\t"
        "v_mov_b32 %3, %1\n\t"
        "s_nop 1\n\t"
        "v_permlane32_swap_b32 %0, %2\n\t"
        "v_permlane32_swap_b32 %1, %3\n\t"
        "s_nop 0\n\t"
        "v_permlane16_swap_b32 %0, %2\n\t"
        "v_permlane16_swap_b32 %1, %3"
        : "+v"(ph0), "+v"(ph1), "=&v"(c0), "=&v"(c1));
    w0 = ph0;
    w1 = ph1;
    w2 = c0;
    w3 = c1;
  };

  for (int t = 0; t < T_LEN; t += 2) {
    step(pxA, pxB, t);
    step(pxB, pxA, t + 1);
  }

  // write last h (f32): lane (hi, cs) holds units 4hi..4hi+3 of seq; unit 15 == 0
  float4 outv = make_float4(harr[0], harr[1], harr[2], harr[3]);
  *reinterpret_cast<float4*>(h_out + (size_t)seq * 16 + 4 * hi) = outv;
}

// Head: y = relu(h @ W1^T + b1) @ W2^T + b2. Block = 256 threads handles 64 batch rows;
// each row by 4 threads (16 output units each).
__global__ __launch_bounds__(256) void head_mlp_kernel(
    const float* __restrict__ h_ws, const float* __restrict__ W1,
    const float* __restrict__ b1, const float* __restrict__ W2,
    const float* __restrict__ b2, float* __restrict__ out) {
  __shared__ float sW1[64][17];
  __shared__ float sW2[64][65];
  __shared__ float sh[64][17];
  __shared__ float sy[64][65];
  __shared__ float sb1[64];
  __shared__ float sb2[64];

  const int tid = threadIdx.x;
  for (int i = tid; i < 64 * 16; i += 256) {
    const int u = i >> 4, k = i & 15;
    sW1[u][k] = (k < 15) ? W1[u * 15 + k] : 0.0f;
  }
  if (tid < 64) {
    sb1[tid] = b1[tid];
    sb2[tid] = b2[tid];
  }
  for (int i = tid; i < 64 * 64; i += 256) sW2[i >> 6][i & 63] = W2[i];
  for (int i = tid; i < 64 * 16; i += 256) sh[i >> 4][i & 15] = h_ws[(size_t)blockIdx.x * 1024 + i];
  __syncthreads();

  const int r = tid >> 2;  // local batch row
  const int q = tid & 3;   // quarter of the 64 outputs

  float y1v[16];
#pragma unroll
  for (int j = 0; j < 16; ++j) {
    const int u = q * 16 + j;
    float a = sb1[u];
#pragma unroll
    for (int k = 0; k < 15; ++k) a = fmaf(sW1[u][k], sh[r][k], a);
    y1v[j] = fmaxf(a, 0.0f);
  }
#pragma unroll
  for (int j = 0; j < 16; ++j) sy[r][q * 16 + j] = y1v[j];
  __syncthreads();

  float yv[64];
#pragma unroll
  for (int k = 0; k < 64; ++k) yv[k] = sy[r][k];
  float o[16];
#pragma unroll
  for (int j = 0; j < 16; ++j) {
    const int u = q * 16 + j;
    float a = sb2[u];
#pragma unroll
    for (int k = 0; k < 64; ++k) a = fmaf(sW2[u][k], yv[k], a);
    o[j] = a;
  }

  float* op = out + ((size_t)(blockIdx.x * 64 + r)) * 64 + q * 16;
#pragma unroll
  for (int j = 0; j < 16; ++j) op[j] = o[j];
}

extern "C" void kernel_launch(void* const* d_in, const int* in_sizes, int n_in,
                              void* d_out, int out_size, void* d_ws, size_t ws_size,
                              hipStream_t stream) {
  (void)in_sizes;
  (void)n_in;
  (void)out_size;
  (void)ws_size;
  const float* x = (const float*)d_in[0];
  const float* W_ih = (const float*)d_in[1];
  const float* W_hh = (const float*)d_in[2];
  const float* b_ih = (const float*)d_in[3];
  const float* b_hh = (const float*)d_in[4];
  const float* W1 = (const float*)d_in[5];
  const float* b1 = (const float*)d_in[6];
  const float* W2 = (const float*)d_in[7];
  const float* b2 = (const float*)d_in[8];
  float* out = (float*)d_out;
  float* h_ws = (float*)d_ws;  // [B][16] floats = 1 MB

  lstm_scan_mfma<<<B_TOT / 64, 256, 0, stream>>>(x, W_ih, W_hh, b_ih, b_hh, h_ws);
  head_mlp_kernel<<<B_TOT / 64, 256, 0, stream>>>(h_ws, W1, b1, W2, b2, out);
}

// Round 8
// 199.217 us; speedup vs baseline: 2.0482x; 1.1349x over previous
//
#include <hip/hip_runtime.h>
#include <hip/hip_bf16.h>

#define B_TOT 16384
#define T_LEN 512
// H = 15 padded to 16. Wave = 16 seqs. Per step:
//   gates[16 rows][16 seqs] = MFMA_h( A=[Whh_hi | Whh_lo], B=[h | h] ) + px
//   px = MFMA_x( A=[Wih_hi(3) | Wih_lo(3)], B=[x_hi x3 dup] ) + bias  <- computed one
//        step AHEAD (double-buffered), overlapping the serial recurrent chain.
// Weight precision: full (hi+lo bf16 limbs) for Whh and Wih; h and x single-bf16
// (random per-step quantization noise, contracted by the forget gate).
// Activation fold: i,f,o rows pre-scaled by -log2e, g by +2log2e ->
//   sigma(a)=rcp(1+exp2(acc)), tanh(a)=1-2*rcp(1+exp2(acc)).
// Trans minimization (v_exp/v_rcp occupy VALU ~16cyc/wave64):
//   quad-rcp: R=rcp(Di*Df*Dg*Do) serves all 4 gates (product <= 2^65, safe);
//   paired tanh(c) rcp across r-pairs; c tracked pre-scaled by 2log2e.
//   26 trans/step vs 32.
// State exchange: 2 movs + 2x permlane32_swap + 2x permlane16_swap -> [h|h] B frag.

typedef float f32x4 __attribute__((ext_vector_type(4)));
typedef short bf16x8 __attribute__((ext_vector_type(8)));
typedef unsigned int u32;
typedef u32 u32x4 __attribute__((ext_vector_type(4)));

#define LOG2E 1.4426950408889634f
#define TWOLOG2E 2.8853900817779268f

__device__ __forceinline__ float fast_rcp(float x) { return __builtin_amdgcn_rcpf(x); }
__device__ __forceinline__ float exp2_hw(float x) {
  float r;
  asm("v_exp_f32 %0, %1" : "=v"(r) : "v"(x));
  return r;
}
__device__ __forceinline__ unsigned short f32_to_bf16_rne(float f) {
  u32 u = __float_as_uint(f);
  u = u + 0x7fffu + ((u >> 16) & 1u);
  return (unsigned short)(u >> 16);
}
__device__ __forceinline__ float bf16u_to_f32(unsigned short s) {
  return __uint_as_float(((u32)s) << 16);
}
__device__ __forceinline__ u32 cvt_pk_bf16(float a, float b) {
  u32 r;
  asm("v_cvt_pk_bf16_f32 %0, %1, %2" : "=v"(r) : "v"(a), "v"(b));
  return r;
}

__global__ __launch_bounds__(256, 1) void lstm_scan_mfma(
    const float* __restrict__ x, const float* __restrict__ W_ih,
    const float* __restrict__ W_hh, const float* __restrict__ b_ih,
    const float* __restrict__ b_hh, float* __restrict__ h_out) {
  const int tid = threadIdx.x;
  const int lane = tid & 63;
  const int wave = tid >> 6;
  const int hi = lane >> 4;   // k-slice / C-row-block selector
  const int cs = lane & 15;   // A-row (unit) == B/C-col (seq slot)
  const int seq = blockIdx.x * 64 + wave * 16 + cs;
  const int u = cs;           // weight unit-row this lane supplies for A

  // ---- static A fragments + bias ----
  // Ah: k0-15 = bf16_hi(gs*Whh[u][k]); k16-31 = bf16_lo(gs*Whh[u][k-16])
  // Ax: k0-2 = bf16_hi(gs*Wih[u][0..2]); k3-5 = bf16_lo(gs*Wih[u][0..2]); else 0
  bf16x8 Ah[4], Ax[4];
  f32x4 cbias[4];
#pragma unroll
  for (int g = 0; g < 4; ++g) {
    const float gs = (g == 2) ? TWOLOG2E : (-LOG2E);
#pragma unroll
    for (int e = 0; e < 8; ++e) {
      const int k = 8 * hi + e;
      float vh = 0.0f, vx = 0.0f;
      if (u < 15) {
        if (k < 16) {
          if (k < 15) vh = bf16u_to_f32(f32_to_bf16_rne(gs * W_hh[(g * 15 + u) * 15 + k]));
        } else {
          const int kk = k - 16;
          if (kk < 15) {
            const float w = gs * W_hh[(g * 15 + u) * 15 + kk];
            vh = w - bf16u_to_f32(f32_to_bf16_rne(w));
          }
        }
        if (k < 3) {
          vx = gs * W_ih[(g * 15 + u) * 3 + k];
        } else if (k < 6) {
          const float w = gs * W_ih[(g * 15 + u) * 3 + (k - 3)];
          vx = w - bf16u_to_f32(f32_to_bf16_rne(w));
        }
      }
      Ah[g][e] = (short)f32_to_bf16_rne(vh);
      Ax[g][e] = (short)f32_to_bf16_rne(vx);
    }
#pragma unroll
    for (int r = 0; r < 4; ++r) {
      const int uu = 4 * hi + r;
      cbias[g][r] = (uu < 15) ? gs * (b_ih[g * 15 + uu] + b_hh[g * 15 + uu]) : 0.0f;
    }
  }

  float cscl[4] = {0.0f, 0.0f, 0.0f, 0.0f};  // c * 2log2e
  float harr[4] = {0.0f, 0.0f, 0.0f, 0.0f};
  u32 w0 = 0u, w1 = 0u, w2 = 0u, w3 = 0u;  // B state fragment (h==0)

  const float* xb = x + (size_t)seq * (T_LEN * 3);

  // Bx fragment: words are k-pairs; A k0-2 = Wih_hi, k3-5 = Wih_lo, both x_hi:
  //   w0=(xh0,xh1) w1=(xh2,xh0) w2=(xh1,xh2) w3=0 ; only hi==0 lanes carry data.
  auto make_bx = [&](float xc0, float xc1, float xc2, u32& b0, u32& b1,
                     u32& b2) __attribute__((always_inline)) {
    const u32 p01 = cvt_pk_bf16(xc0, xc1);
    const u32 p20 = cvt_pk_bf16(xc2, xc0);
    const u32 p12 = cvt_pk_bf16(xc1, xc2);
    b0 = (hi == 0) ? p01 : 0u;
    b1 = (hi == 0) ? p20 : 0u;
    b2 = (hi == 0) ? p12 : 0u;
  };

  // ---- prologue: px(0) from x(0); prefetch x(1) ----
  f32x4 pxA[4], pxB[4];
  {
    u32 b0, b1, b2;
    make_bx(xb[0], xb[1], xb[2], b0, b1, b2);
    const bf16x8 Bx = __builtin_bit_cast(bf16x8, (u32x4){b0, b1, b2, 0u});
    pxA[0] = __builtin_amdgcn_mfma_f32_16x16x32_bf16(Ax[0], Bx, cbias[0], 0, 0, 0);
    pxA[1] = __builtin_amdgcn_mfma_f32_16x16x32_bf16(Ax[1], Bx, cbias[1], 0, 0, 0);
    pxA[2] = __builtin_amdgcn_mfma_f32_16x16x32_bf16(Ax[2], Bx, cbias[2], 0, 0, 0);
    pxA[3] = __builtin_amdgcn_mfma_f32_16x16x32_bf16(Ax[3], Bx, cbias[3], 0, 0, 0);
  }
  float nx0 = xb[3], nx1 = xb[4], nx2 = xb[5];  // x(1)

  // one time-step: consume PX (this step's x-proj), produce PXN (next step's)
  auto step = [&](f32x4(&PX)[4], f32x4(&PXN)[4],
                  int tcur) __attribute__((always_inline)) {
    // recurrent MFMA: gates = [Whh_hi|Whh_lo] * [h|h] + px
    const bf16x8 Bh = __builtin_bit_cast(bf16x8, (u32x4){w0, w1, w2, w3});
    f32x4 acc0 = __builtin_amdgcn_mfma_f32_16x16x32_bf16(Ah[0], Bh, PX[0], 0, 0, 0);
    f32x4 acc1 = __builtin_amdgcn_mfma_f32_16x16x32_bf16(Ah[1], Bh, PX[1], 0, 0, 0);
    f32x4 acc2 = __builtin_amdgcn_mfma_f32_16x16x32_bf16(Ah[2], Bh, PX[2], 0, 0, 0);
    f32x4 acc3 = __builtin_amdgcn_mfma_f32_16x16x32_bf16(Ah[3], Bh, PX[3], 0, 0, 0);

    // state-independent: px for step tcur+1 from x(tcur+1), overlaps the chain
    {
      u32 b0, b1, b2;
      make_bx(nx0, nx1, nx2, b0, b1, b2);
      const bf16x8 Bx = __builtin_bit_cast(bf16x8, (u32x4){b0, b1, b2, 0u});
      PXN[0] = __builtin_amdgcn_mfma_f32_16x16x32_bf16(Ax[0], Bx, cbias[0], 0, 0, 0);
      PXN[1] = __builtin_amdgcn_mfma_f32_16x16x32_bf16(Ax[1], Bx, cbias[1], 0, 0, 0);
      PXN[2] = __builtin_amdgcn_mfma_f32_16x16x32_bf16(Ax[2], Bx, cbias[2], 0, 0, 0);
      PXN[3] = __builtin_amdgcn_mfma_f32_16x16x32_bf16(Ax[3], Bx, cbias[3], 0, 0, 0);
    }
    // prefetch x(tcur+2)
    {
      const int tn = (tcur + 2 < T_LEN) ? (tcur + 2) : (T_LEN - 1);
      nx0 = xb[tn * 3 + 0];
      nx1 = xb[tn * 3 + 1];
      nx2 = xb[tn * 3 + 2];
    }

    // ---- phase 1: 16 independent exps, then quad-rcp gate recovery ----
    float Ei[4], Ef[4], Eg[4], Eo[4];
#pragma unroll
    for (int r = 0; r < 4; ++r) {
      Ei[r] = exp2_hw(acc0[r]);
      Ef[r] = exp2_hw(acc1[r]);
      Eg[r] = exp2_hw(acc2[r]);
      Eo[r] = exp2_hw(acc3[r]);
    }
    float ogv[4];
#pragma unroll
    for (int r = 0; r < 4; ++r) {
      const float Di = 1.0f + Ei[r];
      const float Df = 1.0f + Ef[r];
      const float Dg = 1.0f + Eg[r];
      const float Do = 1.0f + Eo[r];
      const float m1 = Di * Df;
      const float m2 = Dg * Do;
      const float R = fast_rcp(m1 * m2);  // product <= ~2^65, no overflow
      const float R1 = R * m2;            // 1/(Di*Df)
      const float R2 = R * m1;            // 1/(Dg*Do)
      const float ig = R1 * Df;           // sigm(i)
      const float fg = R1 * Di;           // sigm(f)
      // tanh(g) * 2log2e, constant folded into the fma
      const float tgs = fmaf(-2.0f * TWOLOG2E, R2 * Do, TWOLOG2E);
      ogv[r] = R2 * Dg;  // sigm(o)
      cscl[r] = fmaf(fg, cscl[r], ig * tgs);  // c * 2log2e
    }

    // ---- phase 2: tanh(c) with paired rcp (clamp keeps Dc finite -> no 0*inf) ----
    float Ec[4];
#pragma unroll
    for (int r = 0; r < 4; ++r) {
      const float cc = fminf(fmaxf(cscl[r], -120.0f), 120.0f);
      Ec[r] = exp2_hw(cc);
    }
    const float Dc0 = 1.0f + Ec[0], Dc1 = 1.0f + Ec[1];
    const float Dc2 = 1.0f + Ec[2], Dc3 = 1.0f + Ec[3];
    const float Ra = fast_rcp(Dc0 * Dc1);
    const float Rb = fast_rcp(Dc2 * Dc3);
    harr[0] = ogv[0] * fmaf(-2.0f, Ra * Dc1, 1.0f);
    harr[1] = ogv[1] * fmaf(-2.0f, Ra * Dc0, 1.0f);
    harr[2] = ogv[2] * fmaf(-2.0f, Rb * Dc3, 1.0f);
    harr[3] = ogv[3] * fmaf(-2.0f, Rb * Dc2, 1.0f);

    // pack h (single bf16) and exchange into the [h|h]-duplicated B fragment
    u32 ph0 = cvt_pk_bf16(harr[0], harr[1]);
    u32 ph1 = cvt_pk_bf16(harr[2], harr[3]);
    u32 c0, c1;
    asm volatile(
        "v_mov_b32 %2, %0\n\t"
        "v_mov_b32 %3, %1\n\t"
        "s_nop 1\n\t"
        "v_permlane32_swap_b32 %0, %2\n\t"
        "v_permlane32_swap_b32 %1, %3\n\t"
        "s_nop 0\n\t"
        "v_permlane16_swap_b32 %0, %2\n\t"
        "v_permlane16_swap_b32 %1, %3"
        : "+v"(ph0), "+v"(ph1), "=&v"(c0), "=&v"(c1));
    w0 = ph0;
    w1 = ph1;
    w2 = c0;
    w3 = c1;
  };

  for (int t = 0; t < T_LEN; t += 2) {
    step(pxA, pxB, t);
    step(pxB, pxA, t + 1);
  }

  // write last h (f32): lane (hi, cs) holds units 4hi..4hi+3 of seq; unit 15 == 0
  float4 outv = make_float4(harr[0], harr[1], harr[2], harr[3]);
  *reinterpret_cast<float4*>(h_out + (size_t)seq * 16 + 4 * hi) = outv;
}

// Head: y = relu(h @ W1^T + b1) @ W2^T + b2. Block = 256 threads handles 64 batch rows;
// each row by 4 threads (16 output units each).
__global__ __launch_bounds__(256) void head_mlp_kernel(
    const float* __restrict__ h_ws, const float* __restrict__ W1,
    const float* __restrict__ b1, const float* __restrict__ W2,
    const float* __restrict__ b2, float* __restrict__ out) {
  __shared__ float sW1[64][17];
  __shared__ float sW2[64][65];
  __shared__ float sh[64][17];
  __shared__ float sy[64][65];
  __shared__ float sb1[64];
  __shared__ float sb2[64];

  const int tid = threadIdx.x;
  for (int i = tid; i < 64 * 16; i += 256) {
    const int u = i >> 4, k = i & 15;
    sW1[u][k] = (k < 15) ? W1[u * 15 + k] : 0.0f;
  }
  if (tid < 64) {
    sb1[tid] = b1[tid];
    sb2[tid] = b2[tid];
  }
  for (int i = tid; i < 64 * 64; i += 256) sW2[i >> 6][i & 63] = W2[i];
  for (int i = tid; i < 64 * 16; i += 256) sh[i >> 4][i & 15] = h_ws[(size_t)blockIdx.x * 1024 + i];
  __syncthreads();

  const int r = tid >> 2;  // local batch row
  const int q = tid & 3;   // quarter of the 64 outputs

  float y1v[16];
#pragma unroll
  for (int j = 0; j < 16; ++j) {
    const int u = q * 16 + j;
    float a = sb1[u];
#pragma unroll
    for (int k = 0; k < 15; ++k) a = fmaf(sW1[u][k], sh[r][k], a);
    y1v[j] = fmaxf(a, 0.0f);
  }
#pragma unroll
  for (int j = 0; j < 16; ++j) sy[r][q * 16 + j] = y1v[j];
  __syncthreads();

  float yv[64];
#pragma unroll
  for (int k = 0; k < 64; ++k) yv[k] = sy[r][k];
  float o[16];
#pragma unroll
  for (int j = 0; j < 16; ++j) {
    const int u = q * 16 + j;
    float a = sb2[u];
#pragma unroll
    for (int k = 0; k < 64; ++k) a = fmaf(sW2[u][k], yv[k], a);
    o[j] = a;
  }

  float* op = out + ((size_t)(blockIdx.x * 64 + r)) * 64 + q * 16;
#pragma unroll
  for (int j = 0; j < 16; ++j) op[j] = o[j];
}

extern "C" void kernel_launch(void* const* d_in, const int* in_sizes, int n_in,
                              void* d_out, int out_size, void* d_ws, size_t ws_size,
                              hipStream_t stream) {
  (void)in_sizes;
  (void)n_in;
  (void)out_size;
  (void)ws_size;
  const float* x = (const float*)d_in[0];
  const float* W_ih = (const float*)d_in[1];
  const float* W_hh = (const float*)d_in[2];
  const float* b_ih = (const float*)d_in[3];
  const float* b_hh = (const float*)d_in[4];
  const float* W1 = (const float*)d_in[5];
  const float* b1 = (const float*)d_in[6];
  const float* W2 = (const float*)d_in[7];
  const float* b2 = (const float*)d_in[8];
  float* out = (float*)d_out;
  float* h_ws = (float*)d_ws;  // [B][16] floats = 1 MB

  lstm_scan_mfma<<<B_TOT / 64, 256, 0, stream>>>(x, W_ih, W_hh, b_ih, b_hh, h_ws);
  head_mlp_kernel<<<B_TOT / 64, 256, 0, stream>>>(h_ws, W1, b1, W2, b2, out);
}